// Round 1
// baseline (1572.364 us; speedup 1.0000x reference)
//
#include <hip/hip_runtime.h>

#define FD 128
#define HD 64

// Fold LN affine into the first-layer weights:
//   h1 = ((x-mu)*rstd*g + b) @ W1 + b1
//      = xc @ (g.*W1) + (b@W1 + b1)   where xc = (x-mu)*rstd
// wt[h][f] = g[f]*W1[f][h]  (transposed for row-streaming), c[h] = b1[h] + sum_f b[f]*W1[f][h]
__global__ void prep_kernel(const float* __restrict__ lng, const float* __restrict__ lnb,
                            const float* __restrict__ W1, const float* __restrict__ b1,
                            float* __restrict__ wt, float* __restrict__ c) {
    int h = threadIdx.x;  // HD threads
    float acc = b1[h];
    for (int f = 0; f < FD; ++f) {
        float w = W1[f * HD + h];
        wt[h * FD + f] = lng[f] * w;
        acc += lnb[f] * w;
    }
    c[h] = acc;
}

// t[n] = sum_{d,f} vector[n,d,f] * Wnu[f] * (pos[n,d] - mc[b,d])
// one wave per node; lane covers 2 consecutive f's per d.
__global__ __launch_bounds__(256) void vec_kernel(
    const float* __restrict__ vec, const float* __restrict__ wnu,
    const float* __restrict__ pos, const float* __restrict__ mc,
    const int* __restrict__ bidx, float* __restrict__ t, int n_nodes)
{
    int wave = (int)((blockIdx.x * blockDim.x + threadIdx.x) >> 6);
    int lane = threadIdx.x & 63;
    if (wave >= n_nodes) return;
    int n = wave;
    int b = bidx[n];
    float2 wn = *reinterpret_cast<const float2*>(wnu + 2 * lane);
    float acc = 0.f;
#pragma unroll
    for (int d = 0; d < 3; ++d) {
        const float* vr = vec + (size_t)(n * 3 + d) * FD;
        float2 v = *reinterpret_cast<const float2*>(vr + 2 * lane);
        float mcv = pos[n * 3 + d] - mc[b * 3 + d];
        acc += (v.x * wn.x + v.y * wn.y) * mcv;
    }
#pragma unroll
    for (int off = 32; off; off >>= 1) acc += __shfl_xor(acc, off);
    if (lane == 0) t[n] = acc;
}

// One thread per node: row in registers, LN in-register, two F->H matvecs with
// wave-uniform weight streaming, silu, H->1 dot, atomic scatter of the trace term.
__global__ __launch_bounds__(256) void mlp_kernel(
    const float* __restrict__ scaler, const int* __restrict__ bidx,
    const float* __restrict__ t,
    const float* __restrict__ wta, const float* __restrict__ ca,
    const float* __restrict__ wtn, const float* __restrict__ cn,
    const float* __restrict__ wa2, const float* __restrict__ ba2,
    const float* __restrict__ wn2, const float* __restrict__ bn2,
    float* __restrict__ out, int n_nodes)
{
    int n = (int)(blockIdx.x * blockDim.x + threadIdx.x);
    if (n >= n_nodes) return;

    float x[FD];
    float s = 0.f, s2 = 0.f;
    const float4* row = reinterpret_cast<const float4*>(scaler + (size_t)n * FD);
#pragma unroll
    for (int k = 0; k < FD / 4; ++k) {
        float4 v = row[k];
        x[4 * k + 0] = v.x; x[4 * k + 1] = v.y;
        x[4 * k + 2] = v.z; x[4 * k + 3] = v.w;
        s += v.x + v.y + v.z + v.w;
        s2 += v.x * v.x + v.y * v.y + v.z * v.z + v.w * v.w;
    }
    float mu = s * (1.f / FD);
    float var = s2 * (1.f / FD) - mu * mu;
    float rstd = rsqrtf(var + 1e-5f);
#pragma unroll
    for (int f = 0; f < FD; ++f) x[f] = (x[f] - mu) * rstd;

    float resa = 0.f, resn = 0.f;
    for (int h = 0; h < HD; ++h) {
        float aa = ca[h], an = cn[h];
        const float* __restrict__ wra = wta + h * FD;
        const float* __restrict__ wrn = wtn + h * FD;
#pragma unroll
        for (int f = 0; f < FD; ++f) {
            aa = fmaf(x[f], wra[f], aa);
            an = fmaf(x[f], wrn[f], an);
        }
        float ya = aa / (1.f + __expf(-aa));
        float yn = an / (1.f + __expf(-an));
        resa = fmaf(ya, wa2[h], resa);
        resn = fmaf(yn, wn2[h], resn);
    }
    float alpha_s = resa + ba2[0];
    float s_gate  = resn + bn2[0];
    float val = alpha_s + (2.f / 3.f) * s_gate * t[n];
    atomicAdd(out + bidx[n], val);
}

extern "C" void kernel_launch(void* const* d_in, const int* in_sizes, int n_in,
                              void* d_out, int out_size, void* d_ws, size_t ws_size,
                              hipStream_t stream) {
    const float* pos    = (const float*)d_in[0];
    const float* mc     = (const float*)d_in[1];
    const float* scaler = (const float*)d_in[2];
    const float* vec    = (const float*)d_in[3];
    const int*   bidx   = (const int*)d_in[4];
    const float* lnag   = (const float*)d_in[5];
    const float* lnab   = (const float*)d_in[6];
    const float* Wa1    = (const float*)d_in[7];
    const float* ba1    = (const float*)d_in[8];
    const float* Wa2    = (const float*)d_in[9];
    const float* ba2    = (const float*)d_in[10];
    const float* lnng   = (const float*)d_in[11];
    const float* lnnb   = (const float*)d_in[12];
    const float* Wn1    = (const float*)d_in[13];
    const float* bn1    = (const float*)d_in[14];
    const float* Wn2    = (const float*)d_in[15];
    const float* bn2    = (const float*)d_in[16];
    const float* Wnu    = (const float*)d_in[17];

    int N = in_sizes[0] / 3;
    int B = in_sizes[1] / 3;

    float* ws  = (float*)d_ws;
    float* wta = ws;
    float* ca  = wta + HD * FD;
    float* wtn = ca + HD;
    float* cn  = wtn + HD * FD;
    float* t   = cn + HD;

    hipMemsetAsync(d_out, 0, (size_t)B * sizeof(float), stream);

    hipLaunchKernelGGL(prep_kernel, dim3(1), dim3(HD), 0, stream, lnag, lnab, Wa1, ba1, wta, ca);
    hipLaunchKernelGGL(prep_kernel, dim3(1), dim3(HD), 0, stream, lnng, lnnb, Wn1, bn1, wtn, cn);

    int blocks1 = (N + 3) / 4;  // one 64-lane wave per node, 4 waves/block
    hipLaunchKernelGGL(vec_kernel, dim3(blocks1), dim3(256), 0, stream,
                       vec, Wnu, pos, mc, bidx, t, N);

    int blocks2 = (N + 255) / 256;
    hipLaunchKernelGGL(mlp_kernel, dim3(blocks2), dim3(256), 0, stream,
                       scaler, bidx, t, wta, ca, wtn, cn, Wa2, ba2, Wn2, bn2,
                       (float*)d_out, N);
}

// Round 2
// 297.618 us; speedup vs baseline: 5.2832x; 5.2832x over previous
//
#include <hip/hip_runtime.h>

#define FD 128            // feature dim
#define HD 64             // hidden dim per MLP
#define NC 128            // combined output cols (64 for MLP-a | 64 for MLP-n)
#define RPB 64            // nodes (rows) per block in mlp kernel

typedef __attribute__((ext_vector_type(8))) short bf16x8;
typedef __attribute__((ext_vector_type(4))) float f32x4;

// round-to-nearest-even float -> bf16 bits
__device__ __forceinline__ unsigned bfr(float x) {
    unsigned u = __float_as_uint(x);
    return (u + 0x7fffu + ((u >> 16) & 1u)) >> 16;
}

// Build W' (LN-gain folded, transposed, bf16): wq[n][f], n<64 -> MLP-a col, n>=64 -> MLP-n col.
// c[n] = b1[n] + sum_f lnb[f]*W1[f][n]  (LN-bias folded into layer bias), w2[n] = second-layer weight.
__global__ void prep_kernel(
    const float* __restrict__ lnag, const float* __restrict__ lnab,
    const float* __restrict__ Wa1, const float* __restrict__ ba1, const float* __restrict__ Wa2,
    const float* __restrict__ lnng, const float* __restrict__ lnnb,
    const float* __restrict__ Wn1, const float* __restrict__ bn1, const float* __restrict__ Wn2,
    unsigned short* __restrict__ wq, float* __restrict__ c, float* __restrict__ w2)
{
    int n = threadIdx.x;  // 0..127
    const float* W  = (n < HD) ? Wa1 : Wn1;
    const float* g  = (n < HD) ? lnag : lnng;
    const float* bb = (n < HD) ? lnab : lnnb;
    const float* b1 = (n < HD) ? ba1 : bn1;
    const float* W2 = (n < HD) ? Wa2 : Wn2;
    int h = n & (HD - 1);
    float accb = b1[h];
    for (int f = 0; f < FD; ++f) {
        float w = W[f * HD + h];
        wq[n * FD + f] = (unsigned short)bfr(g[f] * w);
        accb += bb[f] * w;
    }
    c[n] = accb;
    w2[n] = W2[h];
}

// t[n] = sum_{d,f} vector[n,d,f] * Wnu[f] * (pos[n,d] - mc[b,d])
// 2 nodes per wave, float4 lanes (16B/lane), 32-lane halves.
__global__ __launch_bounds__(256) void vec_kernel(
    const float* __restrict__ vec, const float* __restrict__ wnu,
    const float* __restrict__ pos, const float* __restrict__ mc,
    const int* __restrict__ bidx, float* __restrict__ t, int n_nodes)
{
    int gid = (int)(blockIdx.x * blockDim.x + threadIdx.x);
    int wave = gid >> 6;
    int lane = threadIdx.x & 63;
    int h = lane >> 5, j = lane & 31;
    int node = wave * 2 + h;
    bool valid = node < n_nodes;
    int n = valid ? node : (n_nodes - 1);
    int b = bidx[n];
    float m0 = pos[n * 3 + 0] - mc[b * 3 + 0];
    float m1 = pos[n * 3 + 1] - mc[b * 3 + 1];
    float m2 = pos[n * 3 + 2] - mc[b * 3 + 2];
    const float4* vr = reinterpret_cast<const float4*>(vec + (size_t)n * 3 * FD);
    float4 wn = reinterpret_cast<const float4*>(wnu)[j];
    float4 v0 = vr[j], v1 = vr[32 + j], v2 = vr[64 + j];
    float acc = (v0.x * wn.x + v0.y * wn.y + v0.z * wn.z + v0.w * wn.w) * m0
              + (v1.x * wn.x + v1.y * wn.y + v1.z * wn.z + v1.w * wn.w) * m1
              + (v2.x * wn.x + v2.y * wn.y + v2.z * wn.z + v2.w * wn.w) * m2;
#pragma unroll
    for (int off = 16; off; off >>= 1) acc += __shfl_xor(acc, off);
    if (j == 0 && valid) t[node] = acc;
}

// Fused LN -> (two F->H matvecs as one bf16 MFMA GEMM) -> SiLU -> H->1 dot -> scatter.
// Block: 256 threads (4 waves), 64 nodes. LDS: Xc tile (bf16, swizzled) + W' tile (bf16, swizzled).
__global__ __launch_bounds__(256) void mlp_kernel(
    const float* __restrict__ scaler, const int* __restrict__ bidx, const float* __restrict__ t,
    const unsigned short* __restrict__ wq, const float* __restrict__ c, const float* __restrict__ w2,
    const float* __restrict__ ba2, const float* __restrict__ bn2,
    float* __restrict__ out, int n_nodes)
{
    __shared__ uint4 xs[RPB * 16];   // 64 rows x 16 slots x 16B = 16 KiB
    __shared__ uint4 wsh[NC * 16];   // 128 rows x 16 slots x 16B = 32 KiB

    int tid = threadIdx.x;
    int rowbase = blockIdx.x * RPB;

    // ---- stage W' (global bf16 -> LDS, swizzled) ----
    {
        int n = tid >> 1, half = tid & 1;
        const uint4* src = reinterpret_cast<const uint4*>(wq + n * FD + half * 64);
#pragma unroll
        for (int j = 0; j < 8; ++j) {
            int slot = half * 8 + j;
            wsh[n * 16 + (slot ^ (n & 15))] = src[j];
        }
    }
    // ---- stage Xc: load scaler rows, LayerNorm, bf16-pack, swizzled LDS write ----
    {
        int r = tid >> 2, qd = tid & 3;           // 4 threads per row, 32 floats each
        int node = rowbase + r;
        int gn = node < n_nodes ? node : (n_nodes - 1);
        const float4* rp = reinterpret_cast<const float4*>(scaler + (size_t)gn * FD) + qd * 8;
        float4 v[8];
        float s = 0.f, s2 = 0.f;
#pragma unroll
        for (int i = 0; i < 8; ++i) {
            v[i] = rp[i];
            s  += v[i].x + v[i].y + v[i].z + v[i].w;
            s2 += v[i].x * v[i].x + v[i].y * v[i].y + v[i].z * v[i].z + v[i].w * v[i].w;
        }
        s  += __shfl_xor(s, 1);  s  += __shfl_xor(s, 2);
        s2 += __shfl_xor(s2, 1); s2 += __shfl_xor(s2, 2);
        float mu = s * (1.f / FD);
        float var = s2 * (1.f / FD) - mu * mu;
        float rstd = rsqrtf(var + 1e-5f);
#pragma unroll
        for (int jj = 0; jj < 4; ++jj) {
            float4 a = v[2 * jj], b = v[2 * jj + 1];
            uint4 pk;
            pk.x = bfr((a.x - mu) * rstd) | (bfr((a.y - mu) * rstd) << 16);
            pk.y = bfr((a.z - mu) * rstd) | (bfr((a.w - mu) * rstd) << 16);
            pk.z = bfr((b.x - mu) * rstd) | (bfr((b.y - mu) * rstd) << 16);
            pk.w = bfr((b.z - mu) * rstd) | (bfr((b.w - mu) * rstd) << 16);
            int slot = qd * 4 + jj;
            xs[r * 16 + (slot ^ (r & 15))] = pk;
        }
    }
    __syncthreads();

    // ---- MFMA: each wave computes 16 rows x 128 cols, K=128 ----
    int lane = tid & 63, w = tid >> 6;
    int lrow = lane & 15, lgrp = lane >> 4;

    bf16x8 af[4];
#pragma unroll
    for (int ks = 0; ks < 4; ++ks) {
        int r = w * 16 + lrow;
        af[ks] = *reinterpret_cast<const bf16x8*>(&xs[r * 16 + ((ks * 4 + lgrp) ^ (r & 15))]);
    }
    float pa[4] = {0.f, 0.f, 0.f, 0.f}, pn[4] = {0.f, 0.f, 0.f, 0.f};
#pragma unroll
    for (int tile = 0; tile < 8; ++tile) {
        f32x4 acc = {0.f, 0.f, 0.f, 0.f};
        int n = tile * 16 + lrow;
#pragma unroll
        for (int ks = 0; ks < 4; ++ks) {
            bf16x8 bf = *reinterpret_cast<const bf16x8*>(&wsh[n * 16 + ((ks * 4 + lgrp) ^ (n & 15))]);
            acc = __builtin_amdgcn_mfma_f32_16x16x32_bf16(af[ks], bf, acc, 0, 0, 0);
        }
        // epilogue for this 16-col tile: bias + SiLU + second-layer partial dot
        int col = tile * 16 + lrow;
        float bias = c[col], w2v = w2[col];
#pragma unroll
        for (int r = 0; r < 4; ++r) {
            float h1 = acc[r] + bias;
            float y = h1 / (1.f + __expf(-h1));
            float cb = y * w2v;
            if (tile < 4) pa[r] += cb; else pn[r] += cb;
        }
    }
    // reduce over the 16 lanes holding different cols (same rows)
#pragma unroll
    for (int off = 1; off < 16; off <<= 1) {
#pragma unroll
        for (int r = 0; r < 4; ++r) {
            pa[r] += __shfl_xor(pa[r], off);
            pn[r] += __shfl_xor(pn[r], off);
        }
    }
    if (lrow == 0) {
        float b2a = ba2[0], b2n = bn2[0];
#pragma unroll
        for (int r = 0; r < 4; ++r) {
            int node = rowbase + w * 16 + lgrp * 4 + r;
            if (node < n_nodes) {
                float val = (pa[r] + b2a) + (2.f / 3.f) * (pn[r] + b2n) * t[node];
                atomicAdd(out + bidx[node], val);
            }
        }
    }
}

extern "C" void kernel_launch(void* const* d_in, const int* in_sizes, int n_in,
                              void* d_out, int out_size, void* d_ws, size_t ws_size,
                              hipStream_t stream) {
    const float* pos    = (const float*)d_in[0];
    const float* mc     = (const float*)d_in[1];
    const float* scaler = (const float*)d_in[2];
    const float* vec    = (const float*)d_in[3];
    const int*   bidx   = (const int*)d_in[4];
    const float* lnag   = (const float*)d_in[5];
    const float* lnab   = (const float*)d_in[6];
    const float* Wa1    = (const float*)d_in[7];
    const float* ba1    = (const float*)d_in[8];
    const float* Wa2    = (const float*)d_in[9];
    const float* ba2    = (const float*)d_in[10];
    const float* lnng   = (const float*)d_in[11];
    const float* lnnb   = (const float*)d_in[12];
    const float* Wn1    = (const float*)d_in[13];
    const float* bn1    = (const float*)d_in[14];
    const float* Wn2    = (const float*)d_in[15];
    const float* bn2    = (const float*)d_in[16];
    const float* Wnu    = (const float*)d_in[17];

    int N = in_sizes[0] / 3;
    int B = in_sizes[1] / 3;

    // workspace layout
    unsigned short* wq = (unsigned short*)d_ws;            // NC*FD bf16 = 32 KiB
    float* c  = (float*)((char*)d_ws + NC * FD * 2);       // 128 f32
    float* w2 = c + NC;                                    // 128 f32
    float* t  = w2 + NC;                                   // N f32

    hipMemsetAsync(d_out, 0, (size_t)B * sizeof(float), stream);

    hipLaunchKernelGGL(prep_kernel, dim3(1), dim3(NC), 0, stream,
                       lnag, lnab, Wa1, ba1, Wa2, lnng, lnnb, Wn1, bn1, Wn2, wq, c, w2);

    int vblocks = (N + 7) / 8;  // 8 nodes per 256-thread block
    hipLaunchKernelGGL(vec_kernel, dim3(vblocks), dim3(256), 0, stream,
                       vec, Wnu, pos, mc, bidx, t, N);

    int mblocks = (N + RPB - 1) / RPB;
    hipLaunchKernelGGL(mlp_kernel, dim3(mblocks), dim3(256), 0, stream,
                       scaler, bidx, t, wq, c, w2, ba2, bn2, (float*)d_out, N);
}

// Round 3
// 278.800 us; speedup vs baseline: 5.6397x; 1.0675x over previous
//
#include <hip/hip_runtime.h>

#define FD 128            // feature dim
#define HD 64             // hidden dim per MLP
#define NC 128            // combined output cols (64 MLP-a | 64 MLP-n)
#define RPB 64            // nodes (rows) per block

typedef __attribute__((ext_vector_type(8))) short bf16x8;
typedef __attribute__((ext_vector_type(4))) float f32x4;

__device__ __forceinline__ unsigned bfr(float x) {
    unsigned u = __float_as_uint(x);
    return (u + 0x7fffu + ((u >> 16) & 1u)) >> 16;
}

// Fold LN affine into first-layer weights (bf16, transposed); fold LN bias into layer bias.
__global__ void prep_kernel(
    const float* __restrict__ lnag, const float* __restrict__ lnab,
    const float* __restrict__ Wa1, const float* __restrict__ ba1, const float* __restrict__ Wa2,
    const float* __restrict__ lnng, const float* __restrict__ lnnb,
    const float* __restrict__ Wn1, const float* __restrict__ bn1, const float* __restrict__ Wn2,
    unsigned short* __restrict__ wq, float* __restrict__ c, float* __restrict__ w2)
{
    int n = threadIdx.x;  // 0..127
    const float* W  = (n < HD) ? Wa1 : Wn1;
    const float* g  = (n < HD) ? lnag : lnng;
    const float* bb = (n < HD) ? lnab : lnnb;
    const float* b1 = (n < HD) ? ba1 : bn1;
    const float* W2 = (n < HD) ? Wa2 : Wn2;
    int h = n & (HD - 1);
    float accb = b1[h];
    for (int f = 0; f < FD; ++f) {
        float w = W[f * HD + h];
        wq[n * FD + f] = (unsigned short)bfr(g[f] * w);
        accb += bb[f] * w;
    }
    c[n] = accb;
    w2[n] = W2[h];
}

// Fully fused: per block of 64 nodes --
//  phase W: stage W' (bf16) to LDS (swizzled)
//  phase T: t[n] = sum_{d,f} vector[n,d,f]*Wnu[f]*(pos[n,d]-mc[b,d])  -> LDS
//  phase X: scaler row load + LayerNorm + bf16 pack -> LDS (swizzled)
//  MFMA:    [64x128] @ [128x128] via 16x16x32 bf16, SiLU + H->1 dot epilogue
//  scatter: atomicAdd(out + bidx[n], alpha_s + 2/3 * gate * t)
__global__ __launch_bounds__(256) void fused_kernel(
    const float* __restrict__ scaler, const float* __restrict__ vec,
    const float* __restrict__ wnu, const float* __restrict__ pos,
    const float* __restrict__ mc, const int* __restrict__ bidx,
    const unsigned short* __restrict__ wq, const float* __restrict__ c,
    const float* __restrict__ w2, const float* __restrict__ ba2,
    const float* __restrict__ bn2, float* __restrict__ out, int n_nodes)
{
    __shared__ uint4 wsh[NC * 16];   // 32 KiB
    __shared__ uint4 xs[RPB * 16];   // 16 KiB
    __shared__ float tl[RPB];

    int tid = threadIdx.x;
    int rowbase = blockIdx.x * RPB;
    int lane = tid & 63, w = tid >> 6;

    // ---- phase W: stage W' ----
    {
        int n = tid >> 1, half = tid & 1;
        const uint4* src = reinterpret_cast<const uint4*>(wq + n * FD + half * 64);
#pragma unroll
        for (int j = 0; j < 8; ++j) {
            int slot = half * 8 + j;
            wsh[n * 16 + (slot ^ (n & 15))] = src[j];
        }
    }

    // ---- phase T: vector contraction, 2 nodes per wave-iter ----
    {
        int h = lane >> 5, j = lane & 31;
        float4 wn = reinterpret_cast<const float4*>(wnu)[j];
#pragma unroll
        for (int it = 0; it < 8; ++it) {
            int nl = w * 16 + it * 2 + h;
            int node = rowbase + nl;
            bool valid = node < n_nodes;
            int n = valid ? node : (n_nodes - 1);
            int b = bidx[n];
            float m0 = pos[n * 3 + 0] - mc[b * 3 + 0];
            float m1 = pos[n * 3 + 1] - mc[b * 3 + 1];
            float m2 = pos[n * 3 + 2] - mc[b * 3 + 2];
            const float4* vr = reinterpret_cast<const float4*>(vec + (size_t)n * 3 * FD);
            float4 v0 = vr[j], v1 = vr[32 + j], v2 = vr[64 + j];
            float acc = (v0.x * wn.x + v0.y * wn.y + v0.z * wn.z + v0.w * wn.w) * m0
                      + (v1.x * wn.x + v1.y * wn.y + v1.z * wn.z + v1.w * wn.w) * m1
                      + (v2.x * wn.x + v2.y * wn.y + v2.z * wn.z + v2.w * wn.w) * m2;
#pragma unroll
            for (int off = 16; off; off >>= 1) acc += __shfl_xor(acc, off);
            if (j == 0 && valid) tl[nl] = acc;
        }
    }

    // ---- phase X: scaler + LN -> bf16 LDS ----
    {
        int r = tid >> 2, qd = tid & 3;           // 4 lanes per row, 32 floats each
        int node = rowbase + r;
        int gn = node < n_nodes ? node : (n_nodes - 1);
        const float4* rp = reinterpret_cast<const float4*>(scaler + (size_t)gn * FD) + qd * 8;
        float4 v[8];
        float s = 0.f, s2 = 0.f;
#pragma unroll
        for (int i = 0; i < 8; ++i) {
            v[i] = rp[i];
            s  += v[i].x + v[i].y + v[i].z + v[i].w;
            s2 += v[i].x * v[i].x + v[i].y * v[i].y + v[i].z * v[i].z + v[i].w * v[i].w;
        }
        s  += __shfl_xor(s, 1);  s  += __shfl_xor(s, 2);
        s2 += __shfl_xor(s2, 1); s2 += __shfl_xor(s2, 2);
        float mu = s * (1.f / FD);
        float var = s2 * (1.f / FD) - mu * mu;
        float rstd = rsqrtf(var + 1e-5f);
#pragma unroll
        for (int jj = 0; jj < 4; ++jj) {
            float4 a = v[2 * jj], b = v[2 * jj + 1];
            uint4 pk;
            pk.x = bfr((a.x - mu) * rstd) | (bfr((a.y - mu) * rstd) << 16);
            pk.y = bfr((a.z - mu) * rstd) | (bfr((a.w - mu) * rstd) << 16);
            pk.z = bfr((b.x - mu) * rstd) | (bfr((b.y - mu) * rstd) << 16);
            pk.w = bfr((b.z - mu) * rstd) | (bfr((b.w - mu) * rstd) << 16);
            int slot = qd * 4 + jj;
            xs[r * 16 + (slot ^ (r & 15))] = pk;
        }
    }
    __syncthreads();

    // ---- MFMA: each wave 16 rows x 128 cols, K=128 ----
    int lrow = lane & 15, lgrp = lane >> 4;
    bf16x8 af[4];
#pragma unroll
    for (int ks = 0; ks < 4; ++ks) {
        int r = w * 16 + lrow;
        af[ks] = *reinterpret_cast<const bf16x8*>(&xs[r * 16 + ((ks * 4 + lgrp) ^ (r & 15))]);
    }
    float pa[4] = {0.f, 0.f, 0.f, 0.f}, pn[4] = {0.f, 0.f, 0.f, 0.f};
#pragma unroll
    for (int tile = 0; tile < 8; ++tile) {
        f32x4 acc = {0.f, 0.f, 0.f, 0.f};
        int n = tile * 16 + lrow;
#pragma unroll
        for (int ks = 0; ks < 4; ++ks) {
            bf16x8 bf = *reinterpret_cast<const bf16x8*>(&wsh[n * 16 + ((ks * 4 + lgrp) ^ (n & 15))]);
            acc = __builtin_amdgcn_mfma_f32_16x16x32_bf16(af[ks], bf, acc, 0, 0, 0);
        }
        int col = tile * 16 + lrow;
        float bias = c[col], w2v = w2[col];
#pragma unroll
        for (int r = 0; r < 4; ++r) {
            float h1 = acc[r] + bias;
            float y = h1 / (1.f + __expf(-h1));
            float cb = y * w2v;
            if (tile < 4) pa[r] += cb; else pn[r] += cb;
        }
    }
#pragma unroll
    for (int off = 1; off < 16; off <<= 1) {
#pragma unroll
        for (int r = 0; r < 4; ++r) {
            pa[r] += __shfl_xor(pa[r], off);
            pn[r] += __shfl_xor(pn[r], off);
        }
    }
    if (lrow == 0) {
        float b2a = ba2[0], b2n = bn2[0];
#pragma unroll
        for (int r = 0; r < 4; ++r) {
            int nl = w * 16 + lgrp * 4 + r;
            int node = rowbase + nl;
            if (node < n_nodes) {
                float val = (pa[r] + b2a) + (2.f / 3.f) * (pn[r] + b2n) * tl[nl];
                atomicAdd(out + bidx[node], val);
            }
        }
    }
}

extern "C" void kernel_launch(void* const* d_in, const int* in_sizes, int n_in,
                              void* d_out, int out_size, void* d_ws, size_t ws_size,
                              hipStream_t stream) {
    const float* pos    = (const float*)d_in[0];
    const float* mc     = (const float*)d_in[1];
    const float* scaler = (const float*)d_in[2];
    const float* vec    = (const float*)d_in[3];
    const int*   bidx   = (const int*)d_in[4];
    const float* lnag   = (const float*)d_in[5];
    const float* lnab   = (const float*)d_in[6];
    const float* Wa1    = (const float*)d_in[7];
    const float* ba1    = (const float*)d_in[8];
    const float* Wa2    = (const float*)d_in[9];
    const float* ba2    = (const float*)d_in[10];
    const float* lnng   = (const float*)d_in[11];
    const float* lnnb   = (const float*)d_in[12];
    const float* Wn1    = (const float*)d_in[13];
    const float* bn1    = (const float*)d_in[14];
    const float* Wn2    = (const float*)d_in[15];
    const float* bn2    = (const float*)d_in[16];
    const float* Wnu    = (const float*)d_in[17];

    int N = in_sizes[0] / 3;
    int B = in_sizes[1] / 3;

    unsigned short* wq = (unsigned short*)d_ws;            // NC*FD bf16 = 32 KiB
    float* c  = (float*)((char*)d_ws + NC * FD * 2);       // 128 f32
    float* w2 = c + NC;                                    // 128 f32

    hipMemsetAsync(d_out, 0, (size_t)B * sizeof(float), stream);

    hipLaunchKernelGGL(prep_kernel, dim3(1), dim3(NC), 0, stream,
                       lnag, lnab, Wa1, ba1, Wa2, lnng, lnnb, Wn1, bn1, Wn2, wq, c, w2);

    int blocks = (N + RPB - 1) / RPB;
    hipLaunchKernelGGL(fused_kernel, dim3(blocks), dim3(256), 0, stream,
                       scaler, vec, Wnu, pos, mc, bidx, wq, c, w2, ba2, bn2,
                       (float*)d_out, N);
}

// Round 4
// 277.620 us; speedup vs baseline: 5.6637x; 1.0043x over previous
//
#include <hip/hip_runtime.h>

#define FD 128            // feature dim
#define HD 64             // hidden dim per MLP
#define NC 128            // combined output cols (64 MLP-a | 64 MLP-n)
#define RPB 64            // nodes (rows) per block

typedef __attribute__((ext_vector_type(8))) short bf16x8;
typedef __attribute__((ext_vector_type(4))) float f32x4;

__device__ __forceinline__ unsigned bfr(float x) {
    unsigned u = __float_as_uint(x);
    return (u + 0x7fffu + ((u >> 16) & 1u)) >> 16;
}

// Fold LN affine into first-layer weights (bf16, transposed); fold LN bias into layer bias.
__global__ void prep_kernel(
    const float* __restrict__ lnag, const float* __restrict__ lnab,
    const float* __restrict__ Wa1, const float* __restrict__ ba1, const float* __restrict__ Wa2,
    const float* __restrict__ lnng, const float* __restrict__ lnnb,
    const float* __restrict__ Wn1, const float* __restrict__ bn1, const float* __restrict__ Wn2,
    unsigned short* __restrict__ wq, float* __restrict__ c, float* __restrict__ w2)
{
    int n = threadIdx.x;  // 0..127
    const float* W  = (n < HD) ? Wa1 : Wn1;
    const float* g  = (n < HD) ? lnag : lnng;
    const float* bb = (n < HD) ? lnab : lnnb;
    const float* b1 = (n < HD) ? ba1 : bn1;
    const float* W2 = (n < HD) ? Wa2 : Wn2;
    int h = n & (HD - 1);
    float accb = b1[h];
    for (int f = 0; f < FD; ++f) {
        float w = W[f * HD + h];
        wq[n * FD + f] = (unsigned short)bfr(g[f] * w);
        accb += bb[f] * w;
    }
    c[n] = accb;
    w2[n] = W2[h];
}

// Fused; W' B-fragments are read per-tile straight from global (L2-resident),
// so LDS is only the Xc tile (16 KiB) + t (256 B) -> thread-limited occupancy.
__global__ __launch_bounds__(256) void fused_kernel(
    const float* __restrict__ scaler, const float* __restrict__ vec,
    const float* __restrict__ wnu, const float* __restrict__ pos,
    const float* __restrict__ mc, const int* __restrict__ bidx,
    const unsigned short* __restrict__ wq, const float* __restrict__ c,
    const float* __restrict__ w2, const float* __restrict__ ba2,
    const float* __restrict__ bn2, float* __restrict__ out, int n_nodes)
{
    __shared__ uint4 xs[RPB * 16];   // 16 KiB, XOR-swizzled
    __shared__ float tl[RPB];

    int tid = threadIdx.x;
    int rowbase = blockIdx.x * RPB;
    int lane = tid & 63, w = tid >> 6;

    // ---- phase T: vector contraction, 2 nodes per wave-iter ----
    {
        int h = lane >> 5, j = lane & 31;
        float4 wn = reinterpret_cast<const float4*>(wnu)[j];
#pragma unroll
        for (int it = 0; it < 8; ++it) {
            int nl = w * 16 + it * 2 + h;
            int node = rowbase + nl;
            bool valid = node < n_nodes;
            int n = valid ? node : (n_nodes - 1);
            int b = bidx[n];
            float m0 = pos[n * 3 + 0] - mc[b * 3 + 0];
            float m1 = pos[n * 3 + 1] - mc[b * 3 + 1];
            float m2 = pos[n * 3 + 2] - mc[b * 3 + 2];
            const float4* vr = reinterpret_cast<const float4*>(vec + (size_t)n * 3 * FD);
            float4 v0 = vr[j], v1 = vr[32 + j], v2 = vr[64 + j];
            float acc = (v0.x * wn.x + v0.y * wn.y + v0.z * wn.z + v0.w * wn.w) * m0
                      + (v1.x * wn.x + v1.y * wn.y + v1.z * wn.z + v1.w * wn.w) * m1
                      + (v2.x * wn.x + v2.y * wn.y + v2.z * wn.z + v2.w * wn.w) * m2;
#pragma unroll
            for (int off = 16; off; off >>= 1) acc += __shfl_xor(acc, off);
            if (j == 0 && valid) tl[nl] = acc;
        }
    }

    // ---- phase X: scaler + LN -> bf16 LDS ----
    {
        int r = tid >> 2, qd = tid & 3;           // 4 lanes per row, 32 floats each
        int node = rowbase + r;
        int gn = node < n_nodes ? node : (n_nodes - 1);
        const float4* rp = reinterpret_cast<const float4*>(scaler + (size_t)gn * FD) + qd * 8;
        float4 v[8];
        float s = 0.f, s2 = 0.f;
#pragma unroll
        for (int i = 0; i < 8; ++i) {
            v[i] = rp[i];
            s  += v[i].x + v[i].y + v[i].z + v[i].w;
            s2 += v[i].x * v[i].x + v[i].y * v[i].y + v[i].z * v[i].z + v[i].w * v[i].w;
        }
        s  += __shfl_xor(s, 1);  s  += __shfl_xor(s, 2);
        s2 += __shfl_xor(s2, 1); s2 += __shfl_xor(s2, 2);
        float mu = s * (1.f / FD);
        float var = s2 * (1.f / FD) - mu * mu;
        float rstd = rsqrtf(var + 1e-5f);
#pragma unroll
        for (int jj = 0; jj < 4; ++jj) {
            float4 a = v[2 * jj], b = v[2 * jj + 1];
            uint4 pk;
            pk.x = bfr((a.x - mu) * rstd) | (bfr((a.y - mu) * rstd) << 16);
            pk.y = bfr((a.z - mu) * rstd) | (bfr((a.w - mu) * rstd) << 16);
            pk.z = bfr((b.x - mu) * rstd) | (bfr((b.y - mu) * rstd) << 16);
            pk.w = bfr((b.z - mu) * rstd) | (bfr((b.w - mu) * rstd) << 16);
            int slot = qd * 4 + jj;
            xs[r * 16 + (slot ^ (r & 15))] = pk;
        }
    }
    __syncthreads();

    // ---- MFMA: each wave 16 rows x 128 cols, K=128; B-frags from global wq ----
    int lrow = lane & 15, lgrp = lane >> 4;
    bf16x8 af[4];
#pragma unroll
    for (int ks = 0; ks < 4; ++ks) {
        int r = w * 16 + lrow;
        af[ks] = *reinterpret_cast<const bf16x8*>(&xs[r * 16 + ((ks * 4 + lgrp) ^ (r & 15))]);
    }
    float pa[4] = {0.f, 0.f, 0.f, 0.f}, pn[4] = {0.f, 0.f, 0.f, 0.f};
#pragma unroll
    for (int tile = 0; tile < 8; ++tile) {
        f32x4 acc = {0.f, 0.f, 0.f, 0.f};
        int n = tile * 16 + lrow;
        const bf16x8* brow = reinterpret_cast<const bf16x8*>(wq + n * FD);
#pragma unroll
        for (int ks = 0; ks < 4; ++ks) {
            bf16x8 bf = brow[ks * 4 + lgrp];
            acc = __builtin_amdgcn_mfma_f32_16x16x32_bf16(af[ks], bf, acc, 0, 0, 0);
        }
        int col = tile * 16 + lrow;
        float bias = c[col], w2v = w2[col];
#pragma unroll
        for (int r = 0; r < 4; ++r) {
            float h1 = acc[r] + bias;
            float y = h1 / (1.f + __expf(-h1));
            float cb = y * w2v;
            if (tile < 4) pa[r] += cb; else pn[r] += cb;
        }
    }
#pragma unroll
    for (int off = 1; off < 16; off <<= 1) {
#pragma unroll
        for (int r = 0; r < 4; ++r) {
            pa[r] += __shfl_xor(pa[r], off);
            pn[r] += __shfl_xor(pn[r], off);
        }
    }
    if (lrow == 0) {
        float b2a = ba2[0], b2n = bn2[0];
#pragma unroll
        for (int r = 0; r < 4; ++r) {
            int nl = w * 16 + lgrp * 4 + r;
            int node = rowbase + nl;
            if (node < n_nodes) {
                float val = (pa[r] + b2a) + (2.f / 3.f) * (pn[r] + b2n) * tl[nl];
                atomicAdd(out + bidx[node], val);
            }
        }
    }
}

extern "C" void kernel_launch(void* const* d_in, const int* in_sizes, int n_in,
                              void* d_out, int out_size, void* d_ws, size_t ws_size,
                              hipStream_t stream) {
    const float* pos    = (const float*)d_in[0];
    const float* mc     = (const float*)d_in[1];
    const float* scaler = (const float*)d_in[2];
    const float* vec    = (const float*)d_in[3];
    const int*   bidx   = (const int*)d_in[4];
    const float* lnag   = (const float*)d_in[5];
    const float* lnab   = (const float*)d_in[6];
    const float* Wa1    = (const float*)d_in[7];
    const float* ba1    = (const float*)d_in[8];
    const float* Wa2    = (const float*)d_in[9];
    const float* ba2    = (const float*)d_in[10];
    const float* lnng   = (const float*)d_in[11];
    const float* lnnb   = (const float*)d_in[12];
    const float* Wn1    = (const float*)d_in[13];
    const float* bn1    = (const float*)d_in[14];
    const float* Wn2    = (const float*)d_in[15];
    const float* bn2    = (const float*)d_in[16];
    const float* Wnu    = (const float*)d_in[17];

    int N = in_sizes[0] / 3;
    int B = in_sizes[1] / 3;

    unsigned short* wq = (unsigned short*)d_ws;            // NC*FD bf16 = 32 KiB
    float* c  = (float*)((char*)d_ws + NC * FD * 2);       // 128 f32
    float* w2 = c + NC;                                    // 128 f32

    hipMemsetAsync(d_out, 0, (size_t)B * sizeof(float), stream);

    hipLaunchKernelGGL(prep_kernel, dim3(1), dim3(NC), 0, stream,
                       lnag, lnab, Wa1, ba1, Wa2, lnng, lnnb, Wn1, bn1, Wn2, wq, c, w2);

    int blocks = (N + RPB - 1) / RPB;
    hipLaunchKernelGGL(fused_kernel, dim3(blocks), dim3(256), 0, stream,
                       scaler, vec, Wnu, pos, mc, bidx, wq, c, w2, ba2, bn2,
                       (float*)d_out, N);
}